// Round 4
// baseline (232.561 us; speedup 1.0000x reference)
//
#include <hip/hip_runtime.h>

#define CC 64
#define LL 1024
#define LOG2E 1.44269504f

typedef unsigned short u16;
typedef unsigned int u32;
typedef __attribute__((ext_vector_type(8))) short short8;
typedef __attribute__((ext_vector_type(4))) float floatx4;

// RN ties-away float->bf16 (2 VALU ops)
static __device__ __forceinline__ u16 f2b(float f) {
  return (u16)((__float_as_uint(f) + 0x8000u) >> 16);
}
static __device__ __forceinline__ u32 pk2(float a, float b) {
  return ((__float_as_uint(a) + 0x8000u) >> 16) |
         ((__float_as_uint(b) + 0x8000u) & 0xffff0000u);
}
// 1-op truncating pack: low16 <- hi16(a), high16 <- hi16(b)  (v_perm_b32)
static __device__ __forceinline__ u32 pk2t(float a, float b) {
  return __builtin_amdgcn_perm(__float_as_uint(b), __float_as_uint(a), 0x07060302u);
}
static __device__ __forceinline__ short8 mk8(u32 a, u32 b, u32 c, u32 d) {
  union { u32 u[4]; short8 s; } t;
  t.u[0] = a; t.u[1] = b; t.u[2] = c; t.u[3] = d;
  return t.s;
}

// ---------------- Phase 0: one-time W -> bf16 (+log2e fold on Wq), biases ----
__global__ __launch_bounds__(256) void w_prep(
    const float* __restrict__ Wq, const float* __restrict__ bq,
    const float* __restrict__ Wk, const float* __restrict__ bk,
    const float* __restrict__ Wv, const float* __restrict__ bv,
    u16* __restrict__ whi, float* __restrict__ bsc)
{
  const int idx = blockIdx.x * 256 + threadIdx.x;   // grid 48 -> 12288
  const int m = idx >> 12;
  const float* W = (m == 0) ? Wq : (m == 1) ? Wk : Wv;
  const float w = W[idx & 4095] * ((m == 0) ? LOG2E : 1.0f);
  whi[idx] = f2b(w);
  if (blockIdx.x == 0 && threadIdx.x < 192)
    bsc[threadIdx.x] = (threadIdx.x < 64) ? bq[threadIdx.x] * LOG2E
                     : (threadIdx.x < 128) ? bk[threadIdx.x - 64] : bv[threadIdx.x - 128];
}

// ---------------- Phase 1: QKV projection (unchanged from round 3) -----------
__global__ __launch_bounds__(256) void qkv_kernel(
    const float* __restrict__ x,
    const u16* __restrict__ whi, const float* __restrict__ bsc,
    u16* __restrict__ qT, u16* __restrict__ kT, u16* __restrict__ vO)
{
  __shared__ __align__(16) u16 xh_s[64 * 72];      // [l][c] bf16 (pad 72)
  __shared__ __align__(16) u16 tbuf_s[4 * 16 * 72];// per-wave q/k transpose buf
  __shared__ float b_s[192];

  const int tid  = threadIdx.x;
  const int wave = tid >> 6;
  const int lane = tid & 63;
  const int l16  = lane & 15;
  const int quad = lane >> 4;

  const int bt = blockIdx.x & 63;                  // XCD pin matches attn consumer
  const int l0 = (blockIdx.x >> 6) << 6;           // 64 l's per block

  const int lx = tid & 63;
  const int cg = (tid >> 6) << 4;
  const float* xp = x + ((size_t)bt * CC + cg) * LL + l0 + lx;

  float v0[16];
  #pragma unroll
  for (int e = 0; e < 16; ++e) v0[e] = xp[(size_t)e * LL];
  if (tid < 192) b_s[tid] = bsc[tid];
  #pragma unroll
  for (int e = 0; e < 16; e += 2)
    *(u32*)(xh_s + lx * 72 + cg + e) = pk2(v0[e], v0[e + 1]);
  __syncthreads();

  const u16* xr_h = xh_s + (wave * 16 + l16) * 72 + quad * 8;
  const short8 xh0 = *(const short8*)(xr_h);
  const short8 xh1 = *(const short8*)(xr_h + 32);

  u16* tb = tbuf_s + wave * 1152;

  #pragma unroll
  for (int ot = 0; ot < 12; ++ot) {
    const int m = ot >> 2;
    const int off = (m << 12) + (((ot & 3) * 16 + l16) << 6) + quad * 8;
    const short8 ah0 = *(const short8*)(whi + off);
    const short8 ah1 = *(const short8*)(whi + off + 32);

    floatx4 acc = (floatx4){0.f, 0.f, 0.f, 0.f};
    acc = __builtin_amdgcn_mfma_f32_16x16x32_bf16(ah0, xh0, acc, 0, 0, 0);
    acc = __builtin_amdgcn_mfma_f32_16x16x32_bf16(ah1, xh1, acc, 0, 0, 0);

    float ov[4];
    #pragma unroll
    for (int r = 0; r < 4; ++r)
      ov[r] = acc[r] + b_s[ot * 16 + quad * 4 + r];

    if (ot < 8) {
      uint2 pv;
      pv.x = pk2(ov[0], ov[1]);
      pv.y = pk2(ov[2], ov[3]);
      *(uint2*)(tb + l16 * 72 + (ot & 3) * 16 + quad * 4) = pv;
      if ((ot & 3) == 3) {
        asm volatile("" ::: "memory");
        u16* gdst = ((ot < 4) ? qT : kT) + ((size_t)(bt * LL + l0 + wave * 16)) * CC;
        const int rr = lane >> 3;
        const int c8 = (lane & 7) * 8;
        #pragma unroll
        for (int s2 = 0; s2 < 2; ++s2) {
          const int row = s2 * 8 + rr;
          uint4 val = *(const uint4*)(tb + row * 72 + c8);
          *(uint4*)(gdst + row * CC + c8) = val;   // 128B-contiguous rows
        }
        asm volatile("" ::: "memory");
      }
    } else {
      const int ob = (ot - 8) * 16 + quad * 4;
      u16* vdst = vO + ((size_t)(bt * CC + ob)) * LL + l0 + wave * 16 + l16;
      #pragma unroll
      for (int r = 0; r < 4; ++r)
        vdst[(size_t)r * LL] = f2b(ov[r]);
    }
  }
}

// ---------------- Phase 2: flash attention, j-SPLIT waves --------------------
// grid 1024 = 64 bt (XCD-pinned) x 16 chunks of 64 i. Block owns 64 i-rows;
// wave w owns j-quarter [16w,16w+16) of every 64-j tile -> each wave reads
// only ITS 16 K-rows (2KB/iter) and V b64 fragments (2KB/iter): 4x less LDS
// read traffic than the i-split scheme (round-1 PMC: LDS-BW was the wall).
// PV runs K=32 over even/odd tile pairs; with identity row order the lane's
// 4 S-outputs per tile ARE the A-frag k-slots (q*8+e) -> no shuffles.
// O/lsum are j-partial per wave -> one LDS reduction at the end.
__global__ __launch_bounds__(256, 3) void attn_kernel(
    const u16* __restrict__ qT, const u16* __restrict__ kT,
    const u16* __restrict__ vB, float* __restrict__ out)
{
  __shared__ __align__(16) u16 smem[18432];   // K0|V0|K1|V1, each 64x72 u16
  const int tid  = threadIdx.x;
  const int wave = tid >> 6;
  const int lane = tid & 63;
  const int l16  = lane & 15;
  const int quad = lane >> 4;

  const int bt    = blockIdx.x & 63;          // XCD pin: blockIdx%8 == bt%8
  const int chunk = blockIdx.x >> 6;          // 0..15
  const int i0b   = chunk << 6;               // 64 i rows per BLOCK

  const u16* kbase = kT + (size_t)bt * LL * CC;
  const u16* vbase = vB + (size_t)bt * CC * LL;

  // Q fragments for all 4 i-tiles (B-operand: B[k=c][col=i])
  short8 qf[4][2];
  #pragma unroll
  for (int it4 = 0; it4 < 4; ++it4) {
    const u16* qr = qT + (size_t)bt * LL * CC + (size_t)(i0b + it4 * 16 + l16) * CC + quad * 8;
    qf[it4][0] = *(const short8*)(qr);
    qf[it4][1] = *(const short8*)(qr + 32);
  }

  floatx4 O[4][4];                            // [i-tile][c-tile], j-partial
  #pragma unroll
  for (int a = 0; a < 4; ++a)
    #pragma unroll
    for (int b = 0; b < 4; ++b)
      O[a][b] = (floatx4){0.f, 0.f, 0.f, 0.f};
  float ls[4] = {0.f, 0.f, 0.f, 0.f};         // j-partial lsum per i-tile

  const int r_st = tid >> 2;                  // staged row (true order, no perm)
  const int c_st = (tid & 3) << 4;

  // prologue: tile 0 -> buf0
  {
    uint4 k0 = *(const uint4*)(kbase + (size_t)r_st * CC + c_st);
    uint4 k1 = *(const uint4*)(kbase + (size_t)r_st * CC + c_st + 8);
    uint4 v0 = *(const uint4*)(vbase + (size_t)r_st * LL + c_st);
    uint4 v1 = *(const uint4*)(vbase + (size_t)r_st * LL + c_st + 8);
    *(uint4*)(smem + r_st * 72 + c_st)              = k0;
    *(uint4*)(smem + r_st * 72 + c_st + 8)          = k1;
    *(uint4*)(smem + 4608 + r_st * 72 + c_st)       = v0;
    *(uint4*)(smem + 4608 + r_st * 72 + c_st + 8)   = v1;
  }
  __syncthreads();

  const int krd = (wave * 16 + l16) * 72 + quad * 8;   // wave's own K rows
  const int vrd = l16 * 72 + wave * 16 + quad * 4;     // + ct*1152

  uint2 vA[4];   // even-tile V b64 fragments (held across to the odd iter)
  uint2 ppE[4];  // even-tile packed P

  for (int itp = 0; itp < 8; ++itp) {
    // ================= EVEN iter: it = 2*itp, buffers 0 =================
    {
      const int jb = (2 * itp + 1) << 6;               // prefetch tile it+1
      uint4 rk0 = *(const uint4*)(kbase + (size_t)(jb + r_st) * CC + c_st);
      uint4 rk1 = *(const uint4*)(kbase + (size_t)(jb + r_st) * CC + c_st + 8);
      uint4 rv0 = *(const uint4*)(vbase + (size_t)r_st * LL + jb + c_st);
      uint4 rv1 = *(const uint4*)(vbase + (size_t)r_st * LL + jb + c_st + 8);

      const u16* kt = smem;
      const short8 a0 = *(const short8*)(kt + krd);
      const short8 a1 = *(const short8*)(kt + krd + 32);
      floatx4 S[4];
      __builtin_amdgcn_s_setprio(1);
      #pragma unroll
      for (int it4 = 0; it4 < 4; ++it4) {
        floatx4 acc = (floatx4){0.f, 0.f, 0.f, 0.f};
        acc = __builtin_amdgcn_mfma_f32_16x16x32_bf16(a0, qf[it4][0], acc, 0, 0, 0);
        acc = __builtin_amdgcn_mfma_f32_16x16x32_bf16(a1, qf[it4][1], acc, 0, 0, 0);
        S[it4] = acc;
      }
      __builtin_amdgcn_s_setprio(0);

      const u16* vt = smem + 4608;
      #pragma unroll
      for (int ct = 0; ct < 4; ++ct)
        vA[ct] = *(const uint2*)(vt + ct * 1152 + vrd);

      #pragma unroll
      for (int it4 = 0; it4 < 4; ++it4) {
        const float e0 = __builtin_amdgcn_exp2f(S[it4][0]);
        const float e1 = __builtin_amdgcn_exp2f(S[it4][1]);
        const float e2 = __builtin_amdgcn_exp2f(S[it4][2]);
        const float e3 = __builtin_amdgcn_exp2f(S[it4][3]);
        ls[it4] += (e0 + e1) + (e2 + e3);
        ppE[it4].x = pk2t(e0, e1);
        ppE[it4].y = pk2t(e2, e3);
      }

      // stage tile it+1 -> buf1
      *(uint4*)(smem + 9216 + r_st * 72 + c_st)             = rk0;
      *(uint4*)(smem + 9216 + r_st * 72 + c_st + 8)         = rk1;
      *(uint4*)(smem + 13824 + r_st * 72 + c_st)            = rv0;
      *(uint4*)(smem + 13824 + r_st * 72 + c_st + 8)        = rv1;
      __syncthreads();
    }
    // ================= ODD iter: it = 2*itp+1, buffers 1 =================
    {
      const bool pf = (itp < 7);
      uint4 rk0, rk1, rv0, rv1;
      if (pf) {
        const int jb = (2 * itp + 2) << 6;
        rk0 = *(const uint4*)(kbase + (size_t)(jb + r_st) * CC + c_st);
        rk1 = *(const uint4*)(kbase + (size_t)(jb + r_st) * CC + c_st + 8);
        rv0 = *(const uint4*)(vbase + (size_t)r_st * LL + jb + c_st);
        rv1 = *(const uint4*)(vbase + (size_t)r_st * LL + jb + c_st + 8);
      }

      const u16* kt = smem + 9216;
      const short8 a0 = *(const short8*)(kt + krd);
      const short8 a1 = *(const short8*)(kt + krd + 32);
      floatx4 S[4];
      __builtin_amdgcn_s_setprio(1);
      #pragma unroll
      for (int it4 = 0; it4 < 4; ++it4) {
        floatx4 acc = (floatx4){0.f, 0.f, 0.f, 0.f};
        acc = __builtin_amdgcn_mfma_f32_16x16x32_bf16(a0, qf[it4][0], acc, 0, 0, 0);
        acc = __builtin_amdgcn_mfma_f32_16x16x32_bf16(a1, qf[it4][1], acc, 0, 0, 0);
        S[it4] = acc;
      }
      __builtin_amdgcn_s_setprio(0);

      const u16* vt = smem + 13824;
      uint2 vC[4];
      #pragma unroll
      for (int ct = 0; ct < 4; ++ct)
        vC[ct] = *(const uint2*)(vt + ct * 1152 + vrd);

      uint2 ppO[4];
      #pragma unroll
      for (int it4 = 0; it4 < 4; ++it4) {
        const float e0 = __builtin_amdgcn_exp2f(S[it4][0]);
        const float e1 = __builtin_amdgcn_exp2f(S[it4][1]);
        const float e2 = __builtin_amdgcn_exp2f(S[it4][2]);
        const float e3 = __builtin_amdgcn_exp2f(S[it4][3]);
        ls[it4] += (e0 + e1) + (e2 + e3);
        ppO[it4].x = pk2t(e0, e1);
        ppO[it4].y = pk2t(e2, e3);
      }

      // PV over the tile pair (K=32): A = [P_even | P_odd], B = [V_even | V_odd]
      short8 vb[4];
      #pragma unroll
      for (int ct = 0; ct < 4; ++ct)
        vb[ct] = mk8(vA[ct].x, vA[ct].y, vC[ct].x, vC[ct].y);

      __builtin_amdgcn_s_setprio(1);
      #pragma unroll
      for (int it4 = 0; it4 < 4; ++it4) {
        const short8 pa = mk8(ppE[it4].x, ppE[it4].y, ppO[it4].x, ppO[it4].y);
        #pragma unroll
        for (int ct = 0; ct < 4; ++ct)
          O[it4][ct] = __builtin_amdgcn_mfma_f32_16x16x32_bf16(pa, vb[ct], O[it4][ct], 0, 0, 0);
      }
      __builtin_amdgcn_s_setprio(0);

      if (pf) {
        *(uint4*)(smem + r_st * 72 + c_st)            = rk0;
        *(uint4*)(smem + r_st * 72 + c_st + 8)        = rk1;
        *(uint4*)(smem + 4608 + r_st * 72 + c_st)     = rv0;
        *(uint4*)(smem + 4608 + r_st * 72 + c_st + 8) = rv1;
      }
      __syncthreads();
    }
  }

  // -------- cross-wave reduction of j-partial O and lsum --------
  #pragma unroll
  for (int it4 = 0; it4 < 4; ++it4) {
    ls[it4] += __shfl_xor(ls[it4], 16, 64);   // sum over q within wave
    ls[it4] += __shfl_xor(ls[it4], 32, 64);
  }

  float* red  = (float*)smem;        // [64 c][68] f32  (wave 0 + wave 2)
  float* redB = red + 4352;          // [64 c][68] f32  (wave 1 + wave 3)
  float* lss  = red + 8704;          // [4 w][64 i] f32

  if (wave < 2) {
    float* dst = wave ? redB : red;
    #pragma unroll
    for (int it4 = 0; it4 < 4; ++it4)
      #pragma unroll
      for (int ct = 0; ct < 4; ++ct)
        *(floatx4*)(dst + (ct * 16 + l16) * 68 + it4 * 16 + quad * 4) = O[it4][ct];
  }
  {
    const float lsv = (quad == 0) ? ls[0] : (quad == 1) ? ls[1] : (quad == 2) ? ls[2] : ls[3];
    lss[wave * 64 + quad * 16 + l16] = lsv;   // it-tile == quad
  }
  __syncthreads();

  if (wave >= 2) {
    float* dst = (wave == 3) ? redB : red;
    #pragma unroll
    for (int it4 = 0; it4 < 4; ++it4)
      #pragma unroll
      for (int ct = 0; ct < 4; ++ct)
        #pragma unroll
        for (int r = 0; r < 4; ++r)
          atomicAdd(&dst[(ct * 16 + l16) * 68 + it4 * 16 + quad * 4 + r], O[it4][ct][r]);
  }
  if (tid < 64) {
    const float s = lss[tid] + lss[64 + tid] + lss[128 + tid] + lss[192 + tid];
    lss[tid] = __builtin_amdgcn_rcpf(s);
  }
  __syncthreads();

  // -------- epilogue: scale + store out[bt][c][i] --------
  {
    const int c  = tid >> 2;
    const int kk = tid & 3;
    float* ob = out + ((size_t)(bt * CC + c)) * LL + i0b + kk * 16;
    #pragma unroll
    for (int e = 0; e < 4; ++e) {
      floatx4 o  = *(const floatx4*)(red  + c * 68 + kk * 16 + e * 4);
      floatx4 o2 = *(const floatx4*)(redB + c * 68 + kk * 16 + e * 4);
      floatx4 rl = *(const floatx4*)(lss + kk * 16 + e * 4);
      o = (o + o2) * rl;
      *(floatx4*)(ob + e * 4) = o;
    }
  }
}

extern "C" void kernel_launch(void* const* d_in, const int* in_sizes, int n_in,
                              void* d_out, int out_size, void* d_ws, size_t ws_size,
                              hipStream_t stream) {
  const float* x  = (const float*)d_in[0];
  const float* Wq = (const float*)d_in[1];
  const float* bq = (const float*)d_in[2];
  const float* Wk = (const float*)d_in[3];
  const float* bk = (const float*)d_in[4];
  const float* Wv = (const float*)d_in[5];
  const float* bv = (const float*)d_in[6];
  float* out = (float*)d_out;

  u16* qTp = (u16*)d_ws;                          // 8 MB
  u16* kTp = qTp + (size_t)64 * LL * CC;          // 8 MB
  u16* vp  = kTp + (size_t)64 * LL * CC;          // 8 MB
  u16* whi = vp  + (size_t)64 * LL * CC;          // 24 KB
  float* bsc = (float*)(whi + 3 * 64 * 64);       // 768 B

  w_prep<<<48, 256, 0, stream>>>(Wq, bq, Wk, bk, Wv, bv, whi, bsc);
  qkv_kernel<<<1024, 256, 0, stream>>>(x, whi, bsc, qTp, kTp, vp);
  attn_kernel<<<1024, 256, 0, stream>>>(qTp, kTp, vp, out);
}

// Round 5
// 188.687 us; speedup vs baseline: 1.2325x; 1.2325x over previous
//
#include <hip/hip_runtime.h>

#define CC 64
#define LL 1024
#define LOG2E 1.44269504f

typedef unsigned short u16;
typedef unsigned int u32;
typedef __attribute__((ext_vector_type(8))) short short8;
typedef __attribute__((ext_vector_type(4))) float floatx4;

// RN ties-away float->bf16 (2 VALU ops)
static __device__ __forceinline__ u16 f2b(float f) {
  return (u16)((__float_as_uint(f) + 0x8000u) >> 16);
}
static __device__ __forceinline__ u32 pk2(float a, float b) {
  return ((__float_as_uint(a) + 0x8000u) >> 16) |
         ((__float_as_uint(b) + 0x8000u) & 0xffff0000u);
}
// 1-op truncating pack: low16 <- hi16(a), high16 <- hi16(b)  (v_perm_b32)
static __device__ __forceinline__ u32 pk2t(float a, float b) {
  return __builtin_amdgcn_perm(__float_as_uint(b), __float_as_uint(a), 0x07060302u);
}
static __device__ __forceinline__ short8 mk8(u32 a, u32 b, u32 c, u32 d) {
  union { u32 u[4]; short8 s; } t;
  t.u[0] = a; t.u[1] = b; t.u[2] = c; t.u[3] = d;
  return t.s;
}

// ---------------- Phase 0: one-time W -> bf16 (+log2e fold on Wq), biases ----
__global__ __launch_bounds__(256) void w_prep(
    const float* __restrict__ Wq, const float* __restrict__ bq,
    const float* __restrict__ Wk, const float* __restrict__ bk,
    const float* __restrict__ Wv, const float* __restrict__ bv,
    u16* __restrict__ whi, float* __restrict__ bsc)
{
  const int idx = blockIdx.x * 256 + threadIdx.x;   // grid 48 -> 12288
  const int m = idx >> 12;
  const float* W = (m == 0) ? Wq : (m == 1) ? Wk : Wv;
  const float w = W[idx & 4095] * ((m == 0) ? LOG2E : 1.0f);
  whi[idx] = f2b(w);
  if (blockIdx.x == 0 && threadIdx.x < 192)
    bsc[threadIdx.x] = (threadIdx.x < 64) ? bq[threadIdx.x] * LOG2E
                     : (threadIdx.x < 128) ? bk[threadIdx.x - 64] : bv[threadIdx.x - 128];
}

// ---------------- Phase 1: QKV projection (unchanged) ------------------------
__global__ __launch_bounds__(256) void qkv_kernel(
    const float* __restrict__ x,
    const u16* __restrict__ whi, const float* __restrict__ bsc,
    u16* __restrict__ qT, u16* __restrict__ kT, u16* __restrict__ vO)
{
  __shared__ __align__(16) u16 xh_s[64 * 72];      // [l][c] bf16 (pad 72)
  __shared__ __align__(16) u16 tbuf_s[4 * 16 * 72];// per-wave q/k transpose buf
  __shared__ float b_s[192];

  const int tid  = threadIdx.x;
  const int wave = tid >> 6;
  const int lane = tid & 63;
  const int l16  = lane & 15;
  const int quad = lane >> 4;

  const int bt = blockIdx.x & 63;                  // XCD pin matches attn consumer
  const int l0 = (blockIdx.x >> 6) << 6;           // 64 l's per block

  const int lx = tid & 63;
  const int cg = (tid >> 6) << 4;
  const float* xp = x + ((size_t)bt * CC + cg) * LL + l0 + lx;

  float v0[16];
  #pragma unroll
  for (int e = 0; e < 16; ++e) v0[e] = xp[(size_t)e * LL];
  if (tid < 192) b_s[tid] = bsc[tid];
  #pragma unroll
  for (int e = 0; e < 16; e += 2)
    *(u32*)(xh_s + lx * 72 + cg + e) = pk2(v0[e], v0[e + 1]);
  __syncthreads();

  const u16* xr_h = xh_s + (wave * 16 + l16) * 72 + quad * 8;
  const short8 xh0 = *(const short8*)(xr_h);
  const short8 xh1 = *(const short8*)(xr_h + 32);

  u16* tb = tbuf_s + wave * 1152;

  #pragma unroll
  for (int ot = 0; ot < 12; ++ot) {
    const int m = ot >> 2;
    const int off = (m << 12) + (((ot & 3) * 16 + l16) << 6) + quad * 8;
    const short8 ah0 = *(const short8*)(whi + off);
    const short8 ah1 = *(const short8*)(whi + off + 32);

    floatx4 acc = (floatx4){0.f, 0.f, 0.f, 0.f};
    acc = __builtin_amdgcn_mfma_f32_16x16x32_bf16(ah0, xh0, acc, 0, 0, 0);
    acc = __builtin_amdgcn_mfma_f32_16x16x32_bf16(ah1, xh1, acc, 0, 0, 0);

    float ov[4];
    #pragma unroll
    for (int r = 0; r < 4; ++r)
      ov[r] = acc[r] + b_s[ot * 16 + quad * 4 + r];

    if (ot < 8) {
      uint2 pv;
      pv.x = pk2(ov[0], ov[1]);
      pv.y = pk2(ov[2], ov[3]);
      *(uint2*)(tb + l16 * 72 + (ot & 3) * 16 + quad * 4) = pv;
      if ((ot & 3) == 3) {
        asm volatile("" ::: "memory");
        u16* gdst = ((ot < 4) ? qT : kT) + ((size_t)(bt * LL + l0 + wave * 16)) * CC;
        const int rr = lane >> 3;
        const int c8 = (lane & 7) * 8;
        #pragma unroll
        for (int s2 = 0; s2 < 2; ++s2) {
          const int row = s2 * 8 + rr;
          uint4 val = *(const uint4*)(tb + row * 72 + c8);
          *(uint4*)(gdst + row * CC + c8) = val;   // 128B-contiguous rows
        }
        asm volatile("" ::: "memory");
      }
    } else {
      const int ob = (ot - 8) * 16 + quad * 4;
      u16* vdst = vO + ((size_t)(bt * CC + ob)) * LL + l0 + wave * 16 + l16;
      #pragma unroll
      for (int r = 0; r < 4; ++r)
        vdst[(size_t)r * LL] = f2b(ov[r]);
    }
  }
}

// ---------------- Phase 2: flash attention, j-SPLIT waves, 32-i blocks -------
// grid 2048 = 64 bt (XCD-pinned) x 32 chunks of 32 i. Wave w owns j-quarter
// [16w,16w+16) of every 64-j tile: per-iter LDS reads are 2KB K + 2KB V per
// wave (4x less than i-split). ROUND-4 LESSON: 4 i-tiles/block = ~140 live
// VGPRs -> spilled to scratch (VGPR_Count 84, 115MB scratch writes, 150us).
// This version halves per-wave state (O[2][4]=32, qf[2][2]=16; peak ~110)
// to fit the 128-VGPR cap of 4 blocks/CU. PV runs K=32 over even/odd tile
// pairs; identity row order makes the lane's 4 S-outputs per tile exactly
// the PV A-frag k-slots (j = wave*16 + quad*4 + r) -> no shuffles, no LDS
// for P. O/lsum are j-partial -> 4 per-wave LDS buffers + epilogue sum
// (no atomics).
__global__ __launch_bounds__(256, 4) void attn_kernel(
    const u16* __restrict__ qT, const u16* __restrict__ kT,
    const u16* __restrict__ vB, float* __restrict__ out)
{
  __shared__ __align__(16) u16 smem[18432];   // K0|V0|K1|V1 (64x72 u16 each);
                                              // epilogue: 4x [64c][36] f32
  __shared__ __align__(16) float lss_s[128];  // [4 w][32 i] partial lsums
  const int tid  = threadIdx.x;
  const int wave = tid >> 6;
  const int lane = tid & 63;
  const int l16  = lane & 15;
  const int quad = lane >> 4;

  const int bt    = blockIdx.x & 63;          // XCD pin: blockIdx%8 == bt%8
  const int chunk = blockIdx.x >> 6;          // 0..31
  const int i0b   = chunk << 5;               // 32 i rows per block

  const u16* kbase = kT + (size_t)bt * LL * CC;
  const u16* vbase = vB + (size_t)bt * CC * LL;

  // Q fragments for 2 i-tiles (B-operand: B[k=c][col=i])
  short8 qf[2][2];
  #pragma unroll
  for (int it4 = 0; it4 < 2; ++it4) {
    const u16* qr = qT + (size_t)bt * LL * CC + (size_t)(i0b + it4 * 16 + l16) * CC + quad * 8;
    qf[it4][0] = *(const short8*)(qr);
    qf[it4][1] = *(const short8*)(qr + 32);
  }

  floatx4 O[2][4];                            // [i-tile][c-tile], j-partial
  #pragma unroll
  for (int a = 0; a < 2; ++a)
    #pragma unroll
    for (int b = 0; b < 4; ++b)
      O[a][b] = (floatx4){0.f, 0.f, 0.f, 0.f};
  float ls[2] = {0.f, 0.f};                   // j-partial lsum per i-tile

  const int r_st = tid >> 2;                  // staged row (true order)
  const int c_st = (tid & 3) << 4;

  // prologue: tile 0 -> buf0
  {
    uint4 k0 = *(const uint4*)(kbase + (size_t)r_st * CC + c_st);
    uint4 k1 = *(const uint4*)(kbase + (size_t)r_st * CC + c_st + 8);
    uint4 v0 = *(const uint4*)(vbase + (size_t)r_st * LL + c_st);
    uint4 v1 = *(const uint4*)(vbase + (size_t)r_st * LL + c_st + 8);
    *(uint4*)(smem + r_st * 72 + c_st)              = k0;
    *(uint4*)(smem + r_st * 72 + c_st + 8)          = k1;
    *(uint4*)(smem + 4608 + r_st * 72 + c_st)       = v0;
    *(uint4*)(smem + 4608 + r_st * 72 + c_st + 8)   = v1;
  }
  __syncthreads();

  const int krd = (wave * 16 + l16) * 72 + quad * 8;   // wave's own K rows
  const int vrd = l16 * 72 + wave * 16 + quad * 4;     // + ct*1152

  uint2 vA[4];   // even-tile V b64 fragments (held across to the odd iter)
  uint2 ppE[2];  // even-tile packed P

  for (int itp = 0; itp < 8; ++itp) {
    // ================= EVEN iter: it = 2*itp, buffers 0 =================
    {
      const int jb = (2 * itp + 1) << 6;               // prefetch tile it+1
      uint4 rk0 = *(const uint4*)(kbase + (size_t)(jb + r_st) * CC + c_st);
      uint4 rk1 = *(const uint4*)(kbase + (size_t)(jb + r_st) * CC + c_st + 8);
      uint4 rv0 = *(const uint4*)(vbase + (size_t)r_st * LL + jb + c_st);
      uint4 rv1 = *(const uint4*)(vbase + (size_t)r_st * LL + jb + c_st + 8);

      const u16* kt = smem;
      const short8 a0 = *(const short8*)(kt + krd);
      const short8 a1 = *(const short8*)(kt + krd + 32);
      floatx4 S[2];
      __builtin_amdgcn_s_setprio(1);
      #pragma unroll
      for (int it4 = 0; it4 < 2; ++it4) {
        floatx4 acc = (floatx4){0.f, 0.f, 0.f, 0.f};
        acc = __builtin_amdgcn_mfma_f32_16x16x32_bf16(a0, qf[it4][0], acc, 0, 0, 0);
        acc = __builtin_amdgcn_mfma_f32_16x16x32_bf16(a1, qf[it4][1], acc, 0, 0, 0);
        S[it4] = acc;
      }
      __builtin_amdgcn_s_setprio(0);

      const u16* vt = smem + 4608;
      #pragma unroll
      for (int ct = 0; ct < 4; ++ct)
        vA[ct] = *(const uint2*)(vt + ct * 1152 + vrd);

      #pragma unroll
      for (int it4 = 0; it4 < 2; ++it4) {
        const float e0 = __builtin_amdgcn_exp2f(S[it4][0]);
        const float e1 = __builtin_amdgcn_exp2f(S[it4][1]);
        const float e2 = __builtin_amdgcn_exp2f(S[it4][2]);
        const float e3 = __builtin_amdgcn_exp2f(S[it4][3]);
        ls[it4] += (e0 + e1) + (e2 + e3);
        ppE[it4].x = pk2t(e0, e1);
        ppE[it4].y = pk2t(e2, e3);
      }

      // stage tile it+1 -> buf1
      *(uint4*)(smem + 9216 + r_st * 72 + c_st)             = rk0;
      *(uint4*)(smem + 9216 + r_st * 72 + c_st + 8)         = rk1;
      *(uint4*)(smem + 13824 + r_st * 72 + c_st)            = rv0;
      *(uint4*)(smem + 13824 + r_st * 72 + c_st + 8)        = rv1;
      __syncthreads();
    }
    // ================= ODD iter: it = 2*itp+1, buffers 1 =================
    {
      const bool pf = (itp < 7);
      uint4 rk0, rk1, rv0, rv1;
      if (pf) {
        const int jb = (2 * itp + 2) << 6;
        rk0 = *(const uint4*)(kbase + (size_t)(jb + r_st) * CC + c_st);
        rk1 = *(const uint4*)(kbase + (size_t)(jb + r_st) * CC + c_st + 8);
        rv0 = *(const uint4*)(vbase + (size_t)r_st * LL + jb + c_st);
        rv1 = *(const uint4*)(vbase + (size_t)r_st * LL + jb + c_st + 8);
      }

      const u16* kt = smem + 9216;
      const short8 a0 = *(const short8*)(kt + krd);
      const short8 a1 = *(const short8*)(kt + krd + 32);
      floatx4 S[2];
      __builtin_amdgcn_s_setprio(1);
      #pragma unroll
      for (int it4 = 0; it4 < 2; ++it4) {
        floatx4 acc = (floatx4){0.f, 0.f, 0.f, 0.f};
        acc = __builtin_amdgcn_mfma_f32_16x16x32_bf16(a0, qf[it4][0], acc, 0, 0, 0);
        acc = __builtin_amdgcn_mfma_f32_16x16x32_bf16(a1, qf[it4][1], acc, 0, 0, 0);
        S[it4] = acc;
      }
      __builtin_amdgcn_s_setprio(0);

      const u16* vt = smem + 13824;
      uint2 vC[4];
      #pragma unroll
      for (int ct = 0; ct < 4; ++ct)
        vC[ct] = *(const uint2*)(vt + ct * 1152 + vrd);

      uint2 ppO[2];
      #pragma unroll
      for (int it4 = 0; it4 < 2; ++it4) {
        const float e0 = __builtin_amdgcn_exp2f(S[it4][0]);
        const float e1 = __builtin_amdgcn_exp2f(S[it4][1]);
        const float e2 = __builtin_amdgcn_exp2f(S[it4][2]);
        const float e3 = __builtin_amdgcn_exp2f(S[it4][3]);
        ls[it4] += (e0 + e1) + (e2 + e3);
        ppO[it4].x = pk2t(e0, e1);
        ppO[it4].y = pk2t(e2, e3);
      }

      // PV over the tile pair (K=32): A = [P_even | P_odd], B = [V_even | V_odd]
      short8 vb[4];
      #pragma unroll
      for (int ct = 0; ct < 4; ++ct)
        vb[ct] = mk8(vA[ct].x, vA[ct].y, vC[ct].x, vC[ct].y);

      __builtin_amdgcn_s_setprio(1);
      #pragma unroll
      for (int it4 = 0; it4 < 2; ++it4) {
        const short8 pa = mk8(ppE[it4].x, ppE[it4].y, ppO[it4].x, ppO[it4].y);
        #pragma unroll
        for (int ct = 0; ct < 4; ++ct)
          O[it4][ct] = __builtin_amdgcn_mfma_f32_16x16x32_bf16(pa, vb[ct], O[it4][ct], 0, 0, 0);
      }
      __builtin_amdgcn_s_setprio(0);

      if (pf) {
        *(uint4*)(smem + r_st * 72 + c_st)            = rk0;
        *(uint4*)(smem + r_st * 72 + c_st + 8)        = rk1;
        *(uint4*)(smem + 4608 + r_st * 72 + c_st)     = rv0;
        *(uint4*)(smem + 4608 + r_st * 72 + c_st + 8) = rv1;
      }
      __syncthreads();
    }
  }

  // -------- cross-wave reduction of j-partial O and lsum (no atomics) ------
  #pragma unroll
  for (int it4 = 0; it4 < 2; ++it4) {
    ls[it4] += __shfl_xor(ls[it4], 16, 64);   // sum over quads within wave
    ls[it4] += __shfl_xor(ls[it4], 32, 64);
  }

  // per-wave buffer: [64 c][36] f32 (36,864 B total for 4 waves, reuses smem)
  {
    float* redw = (float*)smem + wave * 2304;
    #pragma unroll
    for (int it4 = 0; it4 < 2; ++it4)
      #pragma unroll
      for (int ct = 0; ct < 4; ++ct)
        *(floatx4*)(redw + (ct * 16 + l16) * 36 + it4 * 16 + quad * 4) = O[it4][ct];
    if (quad < 2)
      lss_s[wave * 32 + quad * 16 + l16] = ls[quad];
  }
  __syncthreads();

  // -------- epilogue: sum 4 wave-buffers, scale by 1/lsum, store ----------
  {
    const int c  = tid >> 2;
    const int kk = tid & 3;
    float* ob = out + ((size_t)(bt * CC + c)) * LL + i0b + kk * 8;
    #pragma unroll
    for (int e = 0; e < 2; ++e) {
      floatx4 o  = (floatx4){0.f, 0.f, 0.f, 0.f};
      floatx4 sd = (floatx4){0.f, 0.f, 0.f, 0.f};
      #pragma unroll
      for (int w = 0; w < 4; ++w) {
        o  += *(const floatx4*)((float*)smem + w * 2304 + c * 36 + kk * 8 + e * 4);
        sd += *(const floatx4*)(lss_s + w * 32 + kk * 8 + e * 4);
      }
      floatx4 r;
      r[0] = __builtin_amdgcn_rcpf(sd[0]);
      r[1] = __builtin_amdgcn_rcpf(sd[1]);
      r[2] = __builtin_amdgcn_rcpf(sd[2]);
      r[3] = __builtin_amdgcn_rcpf(sd[3]);
      o *= r;
      *(floatx4*)(ob + e * 4) = o;
    }
  }
}

extern "C" void kernel_launch(void* const* d_in, const int* in_sizes, int n_in,
                              void* d_out, int out_size, void* d_ws, size_t ws_size,
                              hipStream_t stream) {
  const float* x  = (const float*)d_in[0];
  const float* Wq = (const float*)d_in[1];
  const float* bq = (const float*)d_in[2];
  const float* Wk = (const float*)d_in[3];
  const float* bk = (const float*)d_in[4];
  const float* Wv = (const float*)d_in[5];
  const float* bv = (const float*)d_in[6];
  float* out = (float*)d_out;

  u16* qTp = (u16*)d_ws;                          // 8 MB
  u16* kTp = qTp + (size_t)64 * LL * CC;          // 8 MB
  u16* vp  = kTp + (size_t)64 * LL * CC;          // 8 MB
  u16* whi = vp  + (size_t)64 * LL * CC;          // 24 KB
  float* bsc = (float*)(whi + 3 * 64 * 64);       // 768 B

  w_prep<<<48, 256, 0, stream>>>(Wq, bq, Wk, bk, Wv, bv, whi, bsc);
  qkv_kernel<<<1024, 256, 0, stream>>>(x, whi, bsc, qTp, kTp, vp);
  attn_kernel<<<2048, 256, 0, stream>>>(qTp, kTp, vp, out);
}

// Round 6
// 125.368 us; speedup vs baseline: 1.8550x; 1.5051x over previous
//
#include <hip/hip_runtime.h>

#define CC 64
#define LL 1024
#define LOG2E 1.44269504f

typedef unsigned short u16;
typedef unsigned int u32;
typedef __attribute__((ext_vector_type(8))) short short8;
typedef __attribute__((ext_vector_type(4))) float floatx4;

// RN ties-away float->bf16 (2 VALU ops)
static __device__ __forceinline__ u16 f2b(float f) {
  return (u16)((__float_as_uint(f) + 0x8000u) >> 16);
}
static __device__ __forceinline__ u32 pk2(float a, float b) {
  return ((__float_as_uint(a) + 0x8000u) >> 16) |
         ((__float_as_uint(b) + 0x8000u) & 0xffff0000u);
}
// 1-op truncating pack: low16 <- hi16(a), high16 <- hi16(b)  (v_perm_b32)
static __device__ __forceinline__ u32 pk2t(float a, float b) {
  return __builtin_amdgcn_perm(__float_as_uint(b), __float_as_uint(a), 0x07060302u);
}
static __device__ __forceinline__ short8 mk8(u32 a, u32 b, u32 c, u32 d) {
  union { u32 u[4]; short8 s; } t;
  t.u[0] = a; t.u[1] = b; t.u[2] = c; t.u[3] = d;
  return t.s;
}

// ---- LDS layout (u16 indices) for the QKV kernel (round-2 variant) ----------
// whi_s : [0, 13824)     3 x [64 o][72] bf16 W, row stride 72 (bank-conflict pad)
// xh_s  : [13824, 23040) 2 x [64 l][72] x-tile bf16
// tbuf  : [23040, 27648) 4 x [16][72] per-wave transpose buf
// b_s   : [27648, 28032) 192 floats
#define LDS_U16 28032

// ---------------- QKV kernel (round-2 known-good: part of the 114.6 best) ----
// grid 512 = 64 bt (XCD-pinned) x 8 l-blocks of 128; 2 l-chunks pipelined.
__global__ __launch_bounds__(256) void qkv_kernel(
    const float* __restrict__ x,
    const float* __restrict__ Wq, const float* __restrict__ bq,
    const float* __restrict__ Wk, const float* __restrict__ bk,
    const float* __restrict__ Wv, const float* __restrict__ bv,
    u16* __restrict__ qT, u16* __restrict__ kT, u16* __restrict__ vO)
{
  __shared__ __align__(16) u16 smem_u[LDS_U16];
  u16* const whi_s  = smem_u;
  u16* const xh_s   = smem_u + 13824;
  u16* const tbuf_s = smem_u + 23040;
  float* const b_s  = (float*)(smem_u + 27648);

  const int tid  = threadIdx.x;
  const int wave = tid >> 6;
  const int lane = tid & 63;
  const int l16  = lane & 15;
  const int quad = lane >> 4;

  const int bt = blockIdx.x & 63;                  // XCD pin matches attn consumer
  const int l0 = (blockIdx.x >> 6) << 7;           // 128 l's per block

  const int lx = tid & 63;
  const int cg = (tid >> 6) << 4;
  const float* xp = x + ((size_t)bt * CC + cg) * LL + l0 + lx;

  // issue chunk-0 x loads first: HBM latency hides under the W-convert loop
  float v0[16];
  #pragma unroll
  for (int e = 0; e < 16; ++e) v0[e] = xp[(size_t)e * LL];

  // one-time (per block) W -> bf16 into padded LDS, log2e folded into Wq
  #pragma unroll
  for (int rep = 0; rep < 24; ++rep) {
    const int i = (rep * 256 + tid) * 2;           // 0..12286, even
    const int m = i >> 12;                         // uniform per rep
    const int r = (i >> 6) & 63;
    const int c = i & 63;
    const int j = i & 4095;
    const float* W = (m == 0) ? Wq : (m == 1) ? Wk : Wv;
    const float sc = (m == 0) ? LOG2E : 1.0f;
    *(u32*)(whi_s + m * 4608 + r * 72 + c) = pk2(W[j] * sc, W[j + 1] * sc);
  }
  if (tid < 192)
    b_s[tid] = (tid < 64) ? bq[tid] * LOG2E
             : (tid < 128) ? bk[tid - 64] : bv[tid - 128];

  #pragma unroll
  for (int e = 0; e < 16; e += 2)
    *(u32*)(xh_s + lx * 72 + cg + e) = pk2(v0[e], v0[e + 1]);
  __syncthreads();

  // prefetch chunk 1 into registers (drains during chunk-0 compute)
  float v1[16];
  #pragma unroll
  for (int e = 0; e < 16; ++e) v1[e] = xp[64 + (size_t)e * LL];

  u16* tb = tbuf_s + wave * 1152;

  auto compute = [&](int ch) {
    const int lc0 = l0 + (ch << 6);
    const u16* xr_h = xh_s + ch * 4608 + (wave * 16 + l16) * 72 + quad * 8;
    const short8 xh0 = *(const short8*)(xr_h);
    const short8 xh1 = *(const short8*)(xr_h + 32);

    #pragma unroll
    for (int ot = 0; ot < 12; ++ot) {
      const int m = ot >> 2;
      const int off = m * 4608 + ((ot & 3) * 16 + l16) * 72 + quad * 8;
      const short8 ah0 = *(const short8*)(whi_s + off);
      const short8 ah1 = *(const short8*)(whi_s + off + 32);

      floatx4 acc = (floatx4){0.f, 0.f, 0.f, 0.f};
      acc = __builtin_amdgcn_mfma_f32_16x16x32_bf16(ah0, xh0, acc, 0, 0, 0);
      acc = __builtin_amdgcn_mfma_f32_16x16x32_bf16(ah1, xh1, acc, 0, 0, 0);

      float ov[4];
      #pragma unroll
      for (int r = 0; r < 4; ++r)
        ov[r] = acc[r] + b_s[ot * 16 + quad * 4 + r];

      if (ot < 8) {
        // D lane holds (o = quad*4+r, l = l16); write transposed [l][o]
        uint2 pv;
        pv.x = pk2(ov[0], ov[1]);
        pv.y = pk2(ov[2], ov[3]);
        *(uint2*)(tb + l16 * 72 + (ot & 3) * 16 + quad * 4) = pv;
        if ((ot & 3) == 3) {
          asm volatile("" ::: "memory");
          u16* gdst = ((ot < 4) ? qT : kT) + ((size_t)(bt * LL + lc0 + wave * 16)) * CC;
          const int rr = lane >> 3;
          const int c8 = (lane & 7) * 8;
          #pragma unroll
          for (int s2 = 0; s2 < 2; ++s2) {
            const int row = s2 * 8 + rr;
            uint4 val = *(const uint4*)(tb + row * 72 + c8);
            *(uint4*)(gdst + row * CC + c8) = val;   // 128B-contiguous rows
          }
          asm volatile("" ::: "memory");
        }
      } else {
        const int ob = (ot - 8) * 16 + quad * 4;
        u16* vdst = vO + ((size_t)(bt * CC + ob)) * LL + lc0 + wave * 16 + l16;
        #pragma unroll
        for (int r = 0; r < 4; ++r)
          vdst[(size_t)r * LL] = f2b(ov[r]);
      }
    }
  };

  compute(0);

  #pragma unroll
  for (int e = 0; e < 16; e += 2)
    *(u32*)(xh_s + 4608 + lx * 72 + cg + e) = pk2(v1[e], v1[e + 1]);
  __syncthreads();

  compute(1);
}

// ---------------- Phase 2: flash attention, j-SPLIT waves, 32-i blocks -------
// grid 2048 = 64 bt (XCD-pinned) x 32 chunks of 32 i. Wave w owns j-quarter
// [16w,16w+16) of every 64-j tile: per-iter LDS reads are 2KB K + 2KB V per
// wave (vs full 8KB+8KB tiles in the i-split scheme).
// ROUND-4/5 LESSON: __launch_bounds__(256,{3,4}) forced arch-VGPR caps of
// 84/64 (accumulators live in the AGPR half of the unified file) -> ~350MB
// scratch spill traffic, 100-150us. PLAIN __launch_bounds__(256) is the
// round-2 known-good precedent (VGPR 88+AGPR, zero spill); LDS (37.4KB)
// still caps residency at 4 blocks/CU.
// PV runs K=32 over even/odd tile pairs; identity row order makes the lane's
// 4 S-outputs per tile exactly the PV A-frag k-slots (j = wave*16+quad*4+r)
// -> no shuffles, no LDS for P. O/lsum are j-partial -> 4 per-wave LDS
// buffers + epilogue sum (no atomics).
__global__ __launch_bounds__(256) void attn_kernel(
    const u16* __restrict__ qT, const u16* __restrict__ kT,
    const u16* __restrict__ vB, float* __restrict__ out)
{
  __shared__ __align__(16) u16 smem[18432];   // K0|V0|K1|V1 (64x72 u16 each);
                                              // epilogue: 4x [64c][36] f32
  __shared__ __align__(16) float lss_s[128];  // [4 w][32 i] partial lsums
  const int tid  = threadIdx.x;
  const int wave = tid >> 6;
  const int lane = tid & 63;
  const int l16  = lane & 15;
  const int quad = lane >> 4;

  const int bt    = blockIdx.x & 63;          // XCD pin: blockIdx%8 == bt%8
  const int chunk = blockIdx.x >> 6;          // 0..31
  const int i0b   = chunk << 5;               // 32 i rows per block

  const u16* kbase = kT + (size_t)bt * LL * CC;
  const u16* vbase = vB + (size_t)bt * CC * LL;

  // Q fragments for 2 i-tiles (B-operand: B[k=c][col=i])
  short8 qf[2][2];
  #pragma unroll
  for (int it4 = 0; it4 < 2; ++it4) {
    const u16* qr = qT + (size_t)bt * LL * CC + (size_t)(i0b + it4 * 16 + l16) * CC + quad * 8;
    qf[it4][0] = *(const short8*)(qr);
    qf[it4][1] = *(const short8*)(qr + 32);
  }

  floatx4 O[2][4];                            // [i-tile][c-tile], j-partial
  #pragma unroll
  for (int a = 0; a < 2; ++a)
    #pragma unroll
    for (int b = 0; b < 4; ++b)
      O[a][b] = (floatx4){0.f, 0.f, 0.f, 0.f};
  float ls[2] = {0.f, 0.f};                   // j-partial lsum per i-tile

  const int r_st = tid >> 2;                  // staged row (true order)
  const int c_st = (tid & 3) << 4;

  // prologue: tile 0 -> buf0
  {
    uint4 k0 = *(const uint4*)(kbase + (size_t)r_st * CC + c_st);
    uint4 k1 = *(const uint4*)(kbase + (size_t)r_st * CC + c_st + 8);
    uint4 v0 = *(const uint4*)(vbase + (size_t)r_st * LL + c_st);
    uint4 v1 = *(const uint4*)(vbase + (size_t)r_st * LL + c_st + 8);
    *(uint4*)(smem + r_st * 72 + c_st)              = k0;
    *(uint4*)(smem + r_st * 72 + c_st + 8)          = k1;
    *(uint4*)(smem + 4608 + r_st * 72 + c_st)       = v0;
    *(uint4*)(smem + 4608 + r_st * 72 + c_st + 8)   = v1;
  }
  __syncthreads();

  const int krd = (wave * 16 + l16) * 72 + quad * 8;   // wave's own K rows
  const int vrd = l16 * 72 + wave * 16 + quad * 4;     // + ct*1152

  uint2 vA[4];   // even-tile V b64 fragments (held across to the odd iter)
  uint2 ppE[2];  // even-tile packed P

  for (int itp = 0; itp < 8; ++itp) {
    // ================= EVEN iter: it = 2*itp, buffers 0 =================
    {
      const int jb = (2 * itp + 1) << 6;               // prefetch tile it+1
      uint4 rk0 = *(const uint4*)(kbase + (size_t)(jb + r_st) * CC + c_st);
      uint4 rk1 = *(const uint4*)(kbase + (size_t)(jb + r_st) * CC + c_st + 8);
      uint4 rv0 = *(const uint4*)(vbase + (size_t)r_st * LL + jb + c_st);
      uint4 rv1 = *(const uint4*)(vbase + (size_t)r_st * LL + jb + c_st + 8);

      const u16* kt = smem;
      const short8 a0 = *(const short8*)(kt + krd);
      const short8 a1 = *(const short8*)(kt + krd + 32);
      floatx4 S[2];
      __builtin_amdgcn_s_setprio(1);
      #pragma unroll
      for (int it4 = 0; it4 < 2; ++it4) {
        floatx4 acc = (floatx4){0.f, 0.f, 0.f, 0.f};
        acc = __builtin_amdgcn_mfma_f32_16x16x32_bf16(a0, qf[it4][0], acc, 0, 0, 0);
        acc = __builtin_amdgcn_mfma_f32_16x16x32_bf16(a1, qf[it4][1], acc, 0, 0, 0);
        S[it4] = acc;
      }
      __builtin_amdgcn_s_setprio(0);

      const u16* vt = smem + 4608;
      #pragma unroll
      for (int ct = 0; ct < 4; ++ct)
        vA[ct] = *(const uint2*)(vt + ct * 1152 + vrd);

      #pragma unroll
      for (int it4 = 0; it4 < 2; ++it4) {
        const float e0 = __builtin_amdgcn_exp2f(S[it4][0]);
        const float e1 = __builtin_amdgcn_exp2f(S[it4][1]);
        const float e2 = __builtin_amdgcn_exp2f(S[it4][2]);
        const float e3 = __builtin_amdgcn_exp2f(S[it4][3]);
        ls[it4] += (e0 + e1) + (e2 + e3);
        ppE[it4].x = pk2t(e0, e1);
        ppE[it4].y = pk2t(e2, e3);
      }

      // stage tile it+1 -> buf1
      *(uint4*)(smem + 9216 + r_st * 72 + c_st)             = rk0;
      *(uint4*)(smem + 9216 + r_st * 72 + c_st + 8)         = rk1;
      *(uint4*)(smem + 13824 + r_st * 72 + c_st)            = rv0;
      *(uint4*)(smem + 13824 + r_st * 72 + c_st + 8)        = rv1;
      __syncthreads();
    }
    // ================= ODD iter: it = 2*itp+1, buffers 1 =================
    {
      const bool pf = (itp < 7);
      uint4 rk0, rk1, rv0, rv1;
      if (pf) {
        const int jb = (2 * itp + 2) << 6;
        rk0 = *(const uint4*)(kbase + (size_t)(jb + r_st) * CC + c_st);
        rk1 = *(const uint4*)(kbase + (size_t)(jb + r_st) * CC + c_st + 8);
        rv0 = *(const uint4*)(vbase + (size_t)r_st * LL + jb + c_st);
        rv1 = *(const uint4*)(vbase + (size_t)r_st * LL + jb + c_st + 8);
      }

      const u16* kt = smem + 9216;
      const short8 a0 = *(const short8*)(kt + krd);
      const short8 a1 = *(const short8*)(kt + krd + 32);
      floatx4 S[2];
      __builtin_amdgcn_s_setprio(1);
      #pragma unroll
      for (int it4 = 0; it4 < 2; ++it4) {
        floatx4 acc = (floatx4){0.f, 0.f, 0.f, 0.f};
        acc = __builtin_amdgcn_mfma_f32_16x16x32_bf16(a0, qf[it4][0], acc, 0, 0, 0);
        acc = __builtin_amdgcn_mfma_f32_16x16x32_bf16(a1, qf[it4][1], acc, 0, 0, 0);
        S[it4] = acc;
      }
      __builtin_amdgcn_s_setprio(0);

      const u16* vt = smem + 13824;
      uint2 vC[4];
      #pragma unroll
      for (int ct = 0; ct < 4; ++ct)
        vC[ct] = *(const uint2*)(vt + ct * 1152 + vrd);

      uint2 ppO[2];
      #pragma unroll
      for (int it4 = 0; it4 < 2; ++it4) {
        const float e0 = __builtin_amdgcn_exp2f(S[it4][0]);
        const float e1 = __builtin_amdgcn_exp2f(S[it4][1]);
        const float e2 = __builtin_amdgcn_exp2f(S[it4][2]);
        const float e3 = __builtin_amdgcn_exp2f(S[it4][3]);
        ls[it4] += (e0 + e1) + (e2 + e3);
        ppO[it4].x = pk2t(e0, e1);
        ppO[it4].y = pk2t(e2, e3);
      }

      // PV over the tile pair (K=32): A = [P_even | P_odd], B = [V_even | V_odd]
      short8 vb[4];
      #pragma unroll
      for (int ct = 0; ct < 4; ++ct)
        vb[ct] = mk8(vA[ct].x, vA[ct].y, vC[ct].x, vC[ct].y);

      __builtin_amdgcn_s_setprio(1);
      #pragma unroll
      for (int it4 = 0; it4 < 2; ++it4) {
        const short8 pa = mk8(ppE[it4].x, ppE[it4].y, ppO[it4].x, ppO[it4].y);
        #pragma unroll
        for (int ct = 0; ct < 4; ++ct)
          O[it4][ct] = __builtin_amdgcn_mfma_f32_16x16x32_bf16(pa, vb[ct], O[it4][ct], 0, 0, 0);
      }
      __builtin_amdgcn_s_setprio(0);

      if (pf) {
        *(uint4*)(smem + r_st * 72 + c_st)            = rk0;
        *(uint4*)(smem + r_st * 72 + c_st + 8)        = rk1;
        *(uint4*)(smem + 4608 + r_st * 72 + c_st)     = rv0;
        *(uint4*)(smem + 4608 + r_st * 72 + c_st + 8) = rv1;
      }
      __syncthreads();
    }
  }

  // -------- cross-wave reduction of j-partial O and lsum (no atomics) ------
  #pragma unroll
  for (int it4 = 0; it4 < 2; ++it4) {
    ls[it4] += __shfl_xor(ls[it4], 16, 64);   // sum over quads within wave
    ls[it4] += __shfl_xor(ls[it4], 32, 64);
  }

  // per-wave buffer: [64 c][36] f32 (36,864 B total for 4 waves, reuses smem)
  {
    float* redw = (float*)smem + wave * 2304;
    #pragma unroll
    for (int it4 = 0; it4 < 2; ++it4)
      #pragma unroll
      for (int ct = 0; ct < 4; ++ct)
        *(floatx4*)(redw + (ct * 16 + l16) * 36 + it4 * 16 + quad * 4) = O[it4][ct];
    if (quad < 2)
      lss_s[wave * 32 + quad * 16 + l16] = ls[quad];
  }
  __syncthreads();

  // -------- epilogue: sum 4 wave-buffers, scale by 1/lsum, store ----------
  {
    const int c  = tid >> 2;
    const int kk = tid & 3;
    float* ob = out + ((size_t)(bt * CC + c)) * LL + i0b + kk * 8;
    #pragma unroll
    for (int e = 0; e < 2; ++e) {
      floatx4 o  = (floatx4){0.f, 0.f, 0.f, 0.f};
      floatx4 sd = (floatx4){0.f, 0.f, 0.f, 0.f};
      #pragma unroll
      for (int w = 0; w < 4; ++w) {
        o  += *(const floatx4*)((float*)smem + w * 2304 + c * 36 + kk * 8 + e * 4);
        sd += *(const floatx4*)(lss_s + w * 32 + kk * 8 + e * 4);
      }
      floatx4 r;
      r[0] = __builtin_amdgcn_rcpf(sd[0]);
      r[1] = __builtin_amdgcn_rcpf(sd[1]);
      r[2] = __builtin_amdgcn_rcpf(sd[2]);
      r[3] = __builtin_amdgcn_rcpf(sd[3]);
      o *= r;
      *(floatx4*)(ob + e * 4) = o;
    }
  }
}

extern "C" void kernel_launch(void* const* d_in, const int* in_sizes, int n_in,
                              void* d_out, int out_size, void* d_ws, size_t ws_size,
                              hipStream_t stream) {
  const float* x  = (const float*)d_in[0];
  const float* Wq = (const float*)d_in[1];
  const float* bq = (const float*)d_in[2];
  const float* Wk = (const float*)d_in[3];
  const float* bk = (const float*)d_in[4];
  const float* Wv = (const float*)d_in[5];
  const float* bv = (const float*)d_in[6];
  float* out = (float*)d_out;

  u16* qTp = (u16*)d_ws;                          // 8 MB
  u16* kTp = qTp + (size_t)64 * LL * CC;          // 8 MB
  u16* vp  = kTp + (size_t)64 * LL * CC;          // 8 MB

  qkv_kernel<<<512, 256, 0, stream>>>(x, Wq, bq, Wk, bk, Wv, bv, qTp, kTp, vp);
  attn_kernel<<<2048, 256, 0, stream>>>(qTp, kTp, vp, out);
}

// Round 7
// 123.525 us; speedup vs baseline: 1.8827x; 1.0149x over previous
//
#include <hip/hip_runtime.h>

#define CC 64
#define LL 1024
#define LOG2E 1.44269504f

typedef unsigned short u16;
typedef unsigned int u32;
typedef __attribute__((ext_vector_type(8))) short short8;
typedef __attribute__((ext_vector_type(4))) float floatx4;

// RN ties-away float->bf16 (2 VALU ops)
static __device__ __forceinline__ u16 f2b(float f) {
  return (u16)((__float_as_uint(f) + 0x8000u) >> 16);
}
static __device__ __forceinline__ u32 pk2(float a, float b) {
  return ((__float_as_uint(a) + 0x8000u) >> 16) |
         ((__float_as_uint(b) + 0x8000u) & 0xffff0000u);
}
// 1-op truncating pack: low16 <- hi16(a), high16 <- hi16(b)  (v_perm_b32)
static __device__ __forceinline__ u32 pk2t(float a, float b) {
  return __builtin_amdgcn_perm(__float_as_uint(b), __float_as_uint(a), 0x07060302u);
}
static __device__ __forceinline__ short8 mk8(u32 a, u32 b, u32 c, u32 d) {
  union { u32 u[4]; short8 s; } t;
  t.u[0] = a; t.u[1] = b; t.u[2] = c; t.u[3] = d;
  return t.s;
}

// ---------------- Phase 0: one-time W -> bf16 (+log2e fold on Wq), biases ----
// whi layout: [3][64 o][64 c] bf16 unpadded; L2-resident for qkv.
__global__ __launch_bounds__(256) void w_prep(
    const float* __restrict__ Wq, const float* __restrict__ bq,
    const float* __restrict__ Wk, const float* __restrict__ bk,
    const float* __restrict__ Wv, const float* __restrict__ bv,
    u16* __restrict__ whi, float* __restrict__ bsc)
{
  const int idx = blockIdx.x * 256 + threadIdx.x;   // grid 48 -> 12288
  const int m = idx >> 12;
  const float* W = (m == 0) ? Wq : (m == 1) ? Wk : Wv;
  const float w = W[idx & 4095] * ((m == 0) ? LOG2E : 1.0f);
  whi[idx] = f2b(w);
  if (blockIdx.x == 0 && threadIdx.x < 192)
    bsc[threadIdx.x] = (threadIdx.x < 64) ? bq[threadIdx.x] * LOG2E
                     : (threadIdx.x < 128) ? bk[threadIdx.x - 64] : bv[threadIdx.x - 128];
}

// ---------------- Phase 1: QKV projection, DIRECT-x (no staging LDS) ---------
// grid 1024 = 64 bt (XCD-pinned) x 16 l-chunks of 64.
// ROUND-6 MEASUREMENT: the fused-W 512-block qkv ran ~32us (vs ~7us HBM
// floor) -- 2 blocks/CU + serial W-convert + long stage chain. Here the
// thread's x-fragment x[c=quad*8+e][l] is loaded DIRECTLY from global:
// per instr the wave touches 4 c-rows x 16 lanes x 4B = fully-used 64B
// segments (coalesced at sector granularity). No x LDS, no barrier; only
// the 9.2KB per-wave transpose buffer remains -> ~8 blocks/CU of TLP.
// W fragments come from L2-resident whi; biases broadcast from bsc.
__global__ __launch_bounds__(256) void qkv_kernel(
    const float* __restrict__ x,
    const u16* __restrict__ whi, const float* __restrict__ bsc,
    u16* __restrict__ qT, u16* __restrict__ kT, u16* __restrict__ vO)
{
  __shared__ __align__(16) u16 tbuf_s[4 * 16 * 72];  // per-wave q/k transpose buf

  const int tid  = threadIdx.x;
  const int wave = tid >> 6;
  const int lane = tid & 63;
  const int l16  = lane & 15;
  const int quad = lane >> 4;

  const int bt = blockIdx.x & 63;                  // XCD pin matches attn consumer
  const int l0 = (blockIdx.x >> 6) << 6;           // 64 l's per block
  const int l  = l0 + wave * 16 + l16;             // this thread's l

  // direct x loads: 16 independent f32 scalars (c = quad*8+e and +32)
  const float* xb = x + (size_t)bt * CC * LL + l;
  float xv0[8], xv1[8];
  #pragma unroll
  for (int e = 0; e < 8; ++e) {
    xv0[e] = xb[(size_t)(quad * 8 + e) * LL];
    xv1[e] = xb[(size_t)(quad * 8 + 32 + e) * LL];
  }
  const short8 xh0 = mk8(pk2(xv0[0], xv0[1]), pk2(xv0[2], xv0[3]),
                         pk2(xv0[4], xv0[5]), pk2(xv0[6], xv0[7]));
  const short8 xh1 = mk8(pk2(xv1[0], xv1[1]), pk2(xv1[2], xv1[3]),
                         pk2(xv1[4], xv1[5]), pk2(xv1[6], xv1[7]));

  u16* tb = tbuf_s + wave * 1152;

  #pragma unroll
  for (int ot = 0; ot < 12; ++ot) {
    const int m = ot >> 2;
    // unpadded whi: fragment rows 128B, tile read 2KB contiguous (L2-hit)
    const int off = (m << 12) + (((ot & 3) * 16 + l16) << 6) + quad * 8;
    const short8 ah0 = *(const short8*)(whi + off);
    const short8 ah1 = *(const short8*)(whi + off + 32);

    floatx4 acc = (floatx4){0.f, 0.f, 0.f, 0.f};
    acc = __builtin_amdgcn_mfma_f32_16x16x32_bf16(ah0, xh0, acc, 0, 0, 0);
    acc = __builtin_amdgcn_mfma_f32_16x16x32_bf16(ah1, xh1, acc, 0, 0, 0);

    const float4 bb = *(const float4*)(bsc + ot * 16 + quad * 4);  // broadcast
    float ov[4];
    ov[0] = acc[0] + bb.x; ov[1] = acc[1] + bb.y;
    ov[2] = acc[2] + bb.z; ov[3] = acc[3] + bb.w;

    if (ot < 8) {
      // D lane holds (o = quad*4+r, l = l16); write transposed [l][o]
      uint2 pv;
      pv.x = pk2(ov[0], ov[1]);
      pv.y = pk2(ov[2], ov[3]);
      *(uint2*)(tb + l16 * 72 + (ot & 3) * 16 + quad * 4) = pv;
      if ((ot & 3) == 3) {
        asm volatile("" ::: "memory");
        u16* gdst = ((ot < 4) ? qT : kT) + ((size_t)(bt * LL + l0 + wave * 16)) * CC;
        const int rr = lane >> 3;
        const int c8 = (lane & 7) * 8;
        #pragma unroll
        for (int s2 = 0; s2 < 2; ++s2) {
          const int row = s2 * 8 + rr;
          uint4 val = *(const uint4*)(tb + row * 72 + c8);
          *(uint4*)(gdst + row * CC + c8) = val;   // 128B-contiguous rows
        }
        asm volatile("" ::: "memory");
      }
    } else {
      const int ob = (ot - 8) * 16 + quad * 4;
      u16* vdst = vO + ((size_t)(bt * CC + ob)) * LL + l0 + wave * 16 + l16;
      #pragma unroll
      for (int r = 0; r < 4; ++r)
        vdst[(size_t)r * LL] = f2b(ov[r]);
    }
  }
}

// ---------------- Phase 2: flash attention (round-2 known-good, i-split) -----
// grid 1024 = 64 bt (XCD-pinned) x 16 chunks of 64 i; 4 waves x 16 i each.
// 36.9KB LDS -> 4 blocks/CU. Double-buffered K/V, ONE barrier/iter. K-row
// permutation trick: K tile rows stored permuted (j=32kt+8q+4b+r -> row
// 32kt+16b+4q+r) so S^T output regs across a tile-pair are exactly the
// K=32 PV A-fragment; P never touches LDS.
__global__ __launch_bounds__(256) void attn_kernel(
    const u16* __restrict__ qT, const u16* __restrict__ kT,
    const u16* __restrict__ vB, float* __restrict__ out)
{
  __shared__ __align__(16) u16 smem[18432];   // 36,864 B: kt0|vt0|kt1|vt1
  const int tid  = threadIdx.x;
  const int wave = tid >> 6;
  const int lane = tid & 63;
  const int l16  = lane & 15;
  const int quad = lane >> 4;

  const int bt    = blockIdx.x & 63;          // XCD pin: blockIdx%8 == bt%8
  const int chunk = blockIdx.x >> 6;          // 0..15
  const int i0w   = (chunk << 6) + (wave << 4);   // 16 i rows per wave

  const u16* kbase = kT + (size_t)bt * LL * CC;
  const u16* vbase = vB + (size_t)bt * CC * LL;

  short8 qf[2];
  {
    const u16* qr = qT + (size_t)bt * LL * CC + (size_t)(i0w + l16) * CC + quad * 8;
    qf[0] = *(const short8*)(qr);
    qf[1] = *(const short8*)(qr + 32);
  }

  floatx4 O[4];
  #pragma unroll
  for (int cf = 0; cf < 4; ++cf)
    O[cf] = (floatx4){0.f, 0.f, 0.f, 0.f};
  float lsA = 0.f, lsB = 0.f;

  const int r_st = tid >> 2;            // global j row this thread stages
  const int c_st = (tid & 3) << 4;
  // sigma(j): j = kt*32 + q*8 + b*4 + r  ->  row = kt*32 + b*16 + q*4 + r
  const int sr = (r_st & 0x20) | ((r_st & 4) << 2) | ((r_st & 0x18) >> 1) | (r_st & 3);

  // prologue: tile 0 -> buf0 (K rows permuted, V rows true)
  {
    uint4 k0 = *(const uint4*)(kbase + (size_t)r_st * CC + c_st);
    uint4 k1 = *(const uint4*)(kbase + (size_t)r_st * CC + c_st + 8);
    uint4 v0 = *(const uint4*)(vbase + (size_t)r_st * LL + c_st);
    uint4 v1 = *(const uint4*)(vbase + (size_t)r_st * LL + c_st + 8);
    *(uint4*)(smem + sr * 72 + c_st)              = k0;
    *(uint4*)(smem + sr * 72 + c_st + 8)          = k1;
    *(uint4*)(smem + 4608 + r_st * 72 + c_st)     = v0;
    *(uint4*)(smem + 4608 + r_st * 72 + c_st + 8) = v1;
  }
  __syncthreads();

  for (int it = 0; it < 16; ++it) {
    u16* ktc = smem + (it & 1) * 9216;
    u16* vtc = ktc + 4608;

    uint4 rk0, rk1, rv0, rv1;
    if (it < 15) {
      const int jb = (it + 1) << 6;
      rk0 = *(const uint4*)(kbase + (size_t)(jb + r_st) * CC + c_st);
      rk1 = *(const uint4*)(kbase + (size_t)(jb + r_st) * CC + c_st + 8);
      rv0 = *(const uint4*)(vbase + (size_t)r_st * LL + jb + c_st);
      rv1 = *(const uint4*)(vbase + (size_t)r_st * LL + jb + c_st + 8);
    }

    // S^T: D[j_perm][i] = sum_c K[j][c] * Q[i][c]  (i = lane&15)
    floatx4 S[4];
    __builtin_amdgcn_s_setprio(1);
    #pragma unroll
    for (int jt = 0; jt < 4; ++jt) {
      const u16* ka = ktc + (jt * 16 + l16) * 72 + quad * 8;
      const short8 a0 = *(const short8*)(ka);
      const short8 a1 = *(const short8*)(ka + 32);
      floatx4 acc = (floatx4){0.f, 0.f, 0.f, 0.f};
      acc = __builtin_amdgcn_mfma_f32_16x16x32_bf16(a0, qf[0], acc, 0, 0, 0);
      acc = __builtin_amdgcn_mfma_f32_16x16x32_bf16(a1, qf[1], acc, 0, 0, 0);
      S[jt] = acc;
    }
    __builtin_amdgcn_s_setprio(0);

    // V fragments issued EARLY: lgkm latency hides under the exp2 block
    short8 v0f[4], v1f[4];
    #pragma unroll
    for (int cf = 0; cf < 4; ++cf) {
      const u16* va = vtc + (cf * 16 + l16) * 72 + quad * 8;
      v0f[cf] = *(const short8*)(va);
      v1f[cf] = *(const short8*)(va + 32);
    }

    // exp2 + partial sums + in-register pack (P stays in VGPRs)
    uint2 pp[4];
    #pragma unroll
    for (int jt = 0; jt < 4; ++jt) {
      const float e0 = __builtin_amdgcn_exp2f(S[jt][0]);
      const float e1 = __builtin_amdgcn_exp2f(S[jt][1]);
      const float e2 = __builtin_amdgcn_exp2f(S[jt][2]);
      const float e3 = __builtin_amdgcn_exp2f(S[jt][3]);
      lsA += e0 + e1;
      lsB += e2 + e3;
      pp[jt].x = pk2t(e0, e1);
      pp[jt].y = pk2t(e2, e3);
    }

    // O += P * V : A = P (in regs, j-order restored by sigma), B = v[c][j]
    __builtin_amdgcn_s_setprio(1);
    {
      const short8 pa0 = mk8(pp[0].x, pp[0].y, pp[1].x, pp[1].y);
      const short8 pa1 = mk8(pp[2].x, pp[2].y, pp[3].x, pp[3].y);
      #pragma unroll
      for (int cf = 0; cf < 4; ++cf) {
        O[cf] = __builtin_amdgcn_mfma_f32_16x16x32_bf16(pa0, v0f[cf], O[cf], 0, 0, 0);
        O[cf] = __builtin_amdgcn_mfma_f32_16x16x32_bf16(pa1, v1f[cf], O[cf], 0, 0, 0);
      }
    }
    __builtin_amdgcn_s_setprio(0);

    if (it < 15) {
      u16* ktn = smem + ((it + 1) & 1) * 9216;
      *(uint4*)(ktn + sr * 72 + c_st)              = rk0;
      *(uint4*)(ktn + sr * 72 + c_st + 8)          = rk1;
      *(uint4*)(ktn + 4608 + r_st * 72 + c_st)     = rv0;
      *(uint4*)(ktn + 4608 + r_st * 72 + c_st + 8) = rv1;
    }
    __syncthreads();
  }

  float lsum = lsA + lsB;
  lsum += __shfl_xor(lsum, 16, 64);
  lsum += __shfl_xor(lsum, 32, 64);

  __syncthreads();   // reuse LDS for epilogue transpose
  float* of = (float*)smem + wave * 1280;   // [64 c][20] per wave
  #pragma unroll
  for (int r = 0; r < 4; ++r) {
    const float rl = __builtin_amdgcn_rcpf(__shfl(lsum, quad * 4 + r, 64));
    #pragma unroll
    for (int cf = 0; cf < 4; ++cf)
      O[cf][r] *= rl;
  }
  asm volatile("" ::: "memory");
  #pragma unroll
  for (int cf = 0; cf < 4; ++cf)
    #pragma unroll
    for (int r = 0; r < 4; ++r)
      of[(cf * 16 + l16) * 20 + quad * 4 + r] = O[cf][r];
  asm volatile("" ::: "memory");
  {
    float* ob = out + ((size_t)bt * CC) * LL + i0w;
    #pragma unroll
    for (int rr = 0; rr < 4; ++rr) {
      const int c = rr * 16 + l16;
      float4 val = *(const float4*)(of + c * 20 + quad * 4);
      *(float4*)(ob + (size_t)c * LL + quad * 4) = val;
    }
  }
  asm volatile("" ::: "memory");
}

extern "C" void kernel_launch(void* const* d_in, const int* in_sizes, int n_in,
                              void* d_out, int out_size, void* d_ws, size_t ws_size,
                              hipStream_t stream) {
  const float* x  = (const float*)d_in[0];
  const float* Wq = (const float*)d_in[1];
  const float* bq = (const float*)d_in[2];
  const float* Wk = (const float*)d_in[3];
  const float* bk = (const float*)d_in[4];
  const float* Wv = (const float*)d_in[5];
  const float* bv = (const float*)d_in[6];
  float* out = (float*)d_out;

  u16* qTp = (u16*)d_ws;                          // 8 MB
  u16* kTp = qTp + (size_t)64 * LL * CC;          // 8 MB
  u16* vp  = kTp + (size_t)64 * LL * CC;          // 8 MB
  u16* whi = vp  + (size_t)64 * LL * CC;          // 24 KB
  float* bsc = (float*)(whi + 3 * 64 * 64);       // 768 B

  w_prep<<<48, 256, 0, stream>>>(Wq, bq, Wk, bk, Wv, bv, whi, bsc);
  qkv_kernel<<<1024, 256, 0, stream>>>(x, whi, bsc, qTp, kTp, vp);
  attn_kernel<<<1024, 256, 0, stream>>>(qTp, kTp, vp, out);
}